// Round 1
// baseline (11368.111 us; speedup 1.0000x reference)
//
#include <hip/hip_runtime.h>
#include <hip/hip_bf16.h>
#include <math.h>

using bf16 = __hip_bfloat16;
typedef __bf16 bf16x8 __attribute__((ext_vector_type(8)));
typedef float f32x4 __attribute__((ext_vector_type(4)));

#define NTOK 65
#define BATCH 256
#define DIM 1024
#define NROWS (BATCH * NTOK) /* 16640 */
#define FDIM 4096
#define NHEADS 16
#define NLAYER 12

__device__ __forceinline__ float b2f(bf16 v) { return __bfloat162float(v); }
__device__ __forceinline__ bf16 f2b(float v) { return __float2bfloat16(v); }

// async global->LDS, 16B per lane; lds ptr must be wave-uniform (lane i lands at base + i*16B)
__device__ __forceinline__ void load16(const void* g, void* l) {
  __builtin_amdgcn_global_load_lds((const __attribute__((address_space(1))) void*)g,
                                   (__attribute__((address_space(3))) void*)l,
                                   16, 0, 0);
}

// ---------------- weight convert + transpose: W (L,K,N) f32 -> Wt (L,N,K) bf16 ----------------
__global__ __launch_bounds__(256) void transpose_w(const float* __restrict__ W,
                                                   bf16* __restrict__ Wt, int K, int Nn) {
  __shared__ float t[32][33];
  int l = blockIdx.z;
  const float* Wl = W + (size_t)l * K * Nn;
  bf16* Wtl = Wt + (size_t)l * K * Nn;
  int n0 = blockIdx.x * 32, k0 = blockIdx.y * 32;
  int tx = threadIdx.x, ty = threadIdx.y; // 32 x 8
  for (int i = 0; i < 4; i++)
    t[ty + i * 8][tx] = Wl[(size_t)(k0 + ty + i * 8) * Nn + n0 + tx];
  __syncthreads();
  for (int i = 0; i < 4; i++)
    Wtl[(size_t)(n0 + ty + i * 8) * K + k0 + tx] = f2b(t[tx][ty + i * 8]);
}

// ---------------- im2col: img (B,1,256,256) f32 -> patches (B*64, 1024) bf16 ----------------
__global__ __launch_bounds__(256) void im2col_k(const float* __restrict__ img, bf16* __restrict__ out) {
  int idx = blockIdx.x * 256 + threadIdx.x; // 16384*1024 total
  int c = idx & 31, r = (idx >> 5) & 31, p = (idx >> 10) & 63, b = idx >> 16;
  int gr = p >> 3, gc = p & 7;
  out[idx] = f2b(img[((size_t)b << 16) + (size_t)(gr * 32 + r) * 256 + gc * 32 + c]);
}

// ---------------- cls rows of residual stream ----------------
__global__ __launch_bounds__(256) void clsfill_k(const float* __restrict__ cls, float* __restrict__ xbuf) {
  int idx = blockIdx.x * 256 + threadIdx.x; // 256*1024
  int b = idx >> 10, d = idx & 1023;
  xbuf[(size_t)(b * NTOK) * DIM + d] = cls[d];
}

// ---------------- LayerNorm: fp32 row (1024) -> bf16 row ----------------
__global__ __launch_bounds__(256) void ln_k(const float* __restrict__ x, const float* __restrict__ g,
                                            const float* __restrict__ bt, bf16* __restrict__ out) {
  int row = blockIdx.x;
  int t = threadIdx.x;
  float4 v = ((const float4*)(x + (size_t)row * DIM))[t];
  float s = v.x + v.y + v.z + v.w;
  float ss = v.x * v.x + v.y * v.y + v.z * v.z + v.w * v.w;
  for (int off = 32; off > 0; off >>= 1) { s += __shfl_down(s, off, 64); ss += __shfl_down(ss, off, 64); }
  __shared__ float sh[8];
  int w = t >> 6, lane = t & 63;
  if (lane == 0) { sh[w] = s; sh[w + 4] = ss; }
  __syncthreads();
  s = sh[0] + sh[1] + sh[2] + sh[3];
  ss = sh[4] + sh[5] + sh[6] + sh[7];
  float mu = s * (1.f / DIM);
  float rs = rsqrtf(ss * (1.f / DIM) - mu * mu + 1e-5f);
  float4 gv = ((const float4*)g)[t];
  float4 bv = ((const float4*)bt)[t];
  bf16* o = out + (size_t)row * DIM + t * 4;
  o[0] = f2b((v.x - mu) * rs * gv.x + bv.x);
  o[1] = f2b((v.y - mu) * rs * gv.y + bv.y);
  o[2] = f2b((v.z - mu) * rs * gv.z + bv.z);
  o[3] = f2b((v.w - mu) * rs * gv.w + bv.w);
}

// ---------------- final LN on cls rows only -> fp32 d_out ----------------
__global__ __launch_bounds__(256) void lnf_k(const float* __restrict__ x, const float* __restrict__ g,
                                             const float* __restrict__ bt, float* __restrict__ out) {
  int b = blockIdx.x;
  int t = threadIdx.x;
  float4 v = ((const float4*)(x + (size_t)(b * NTOK) * DIM))[t];
  float s = v.x + v.y + v.z + v.w;
  float ss = v.x * v.x + v.y * v.y + v.z * v.z + v.w * v.w;
  for (int off = 32; off > 0; off >>= 1) { s += __shfl_down(s, off, 64); ss += __shfl_down(ss, off, 64); }
  __shared__ float sh[8];
  int w = t >> 6, lane = t & 63;
  if (lane == 0) { sh[w] = s; sh[w + 4] = ss; }
  __syncthreads();
  s = sh[0] + sh[1] + sh[2] + sh[3];
  ss = sh[4] + sh[5] + sh[6] + sh[7];
  float mu = s * (1.f / DIM);
  float rs = rsqrtf(ss * (1.f / DIM) - mu * mu + 1e-5f);
  float4 gv = ((const float4*)g)[t];
  float4 bv = ((const float4*)bt)[t];
  float4 o;
  o.x = (v.x - mu) * rs * gv.x + bv.x;
  o.y = (v.y - mu) * rs * gv.y + bv.y;
  o.z = (v.z - mu) * rs * gv.z + bv.z;
  o.w = (v.w - mu) * rs * gv.w + bv.w;
  ((float4*)(out + (size_t)b * DIM))[t] = o;
}

// ---------------- generic NT GEMM: C[M,Nn] = A[M,K](bf16) @ Bt[Nn,K](bf16)^T ----------------
// MODE 0: bf16 out, no bias (QKV)
// MODE 1: bias + exact GELU -> bf16 out (MLP1)
// MODE 2: bias + residual -> fp32 out (proj / MLP2)
// MODE 3: bias + row remap (patch embed: row -> row + row/64 + 1) -> fp32 out
template <int MODE>
__global__ __launch_bounds__(256) void gemm_bt(const bf16* __restrict__ A, const bf16* __restrict__ Bt,
                                               const float* __restrict__ bias, const float* __restrict__ res,
                                               float* __restrict__ outf, bf16* __restrict__ outb,
                                               int M, int Nn, int K) {
  __shared__ __align__(16) bf16 As[128 * 32];
  __shared__ __align__(16) bf16 Bs[128 * 32];
  int tid = threadIdx.x;
  int w = tid >> 6, lane = tid & 63;
  int quad = lane >> 4, lr = lane & 15;
  int m0 = blockIdx.y * 128, n0 = blockIdx.x * 128;
  int srow = w * 32 + (lane >> 2);
  int skoff = (lane & 3) * 8;
  const bf16* Ag = A + (size_t)(m0 + srow) * K + skoff;
  const bf16* Bg = Bt + (size_t)(n0 + srow) * K + skoff;
  bf16* AsW = &As[w * 1024];
  bf16* BsW = &Bs[w * 1024];
  int wm = (w >> 1) * 64, wn = (w & 1) * 64;
  f32x4 acc[4][4];
  for (int i = 0; i < 4; i++)
    for (int j = 0; j < 4; j++) acc[i][j] = (f32x4){0.f, 0.f, 0.f, 0.f};
  for (int kb = 0; kb < K; kb += 32) {
    load16(Ag + kb, AsW);
    load16(Ag + kb + (size_t)16 * K, AsW + 512);
    load16(Bg + kb, BsW);
    load16(Bg + kb + (size_t)16 * K, BsW + 512);
    __syncthreads();
    bf16x8 af[4], bfr[4];
    for (int i = 0; i < 4; i++)
      af[i] = *reinterpret_cast<const bf16x8*>(&As[(wm + i * 16 + lr) * 32 + quad * 8]);
    for (int i = 0; i < 4; i++)
      bfr[i] = *reinterpret_cast<const bf16x8*>(&Bs[(wn + i * 16 + lr) * 32 + quad * 8]);
    for (int mi = 0; mi < 4; mi++)
      for (int ni = 0; ni < 4; ni++)
        acc[mi][ni] = __builtin_amdgcn_mfma_f32_16x16x32_bf16(af[mi], bfr[ni], acc[mi][ni], 0, 0, 0);
    __syncthreads();
  }
  for (int mi = 0; mi < 4; mi++)
    for (int ni = 0; ni < 4; ni++)
      for (int r = 0; r < 4; r++) {
        int grow = m0 + wm + mi * 16 + quad * 4 + r;
        int gcol = n0 + wn + ni * 16 + lr;
        float v = acc[mi][ni][r];
        if (MODE == 0) {
          outb[(size_t)grow * Nn + gcol] = f2b(v);
        } else if (MODE == 1) {
          v += bias[gcol];
          v = 0.5f * v * (1.f + erff(v * 0.70710678118f));
          outb[(size_t)grow * Nn + gcol] = f2b(v);
        } else if (MODE == 2) {
          size_t o = (size_t)grow * Nn + gcol;
          outf[o] = res[o] + v + bias[gcol];
        } else {
          int prow = grow + (grow >> 6) + 1; // b*64+p -> b*65+1+p
          outf[(size_t)prow * DIM + gcol] = v + bias[gcol];
        }
      }
}

// ---------------- attention: one block per (b,h); RoPE on load; MFMA QK^T and PV ----------------
__global__ __launch_bounds__(256) void attn_k(const bf16* __restrict__ qkv, bf16* __restrict__ O) {
  int bh = blockIdx.x;
  int b = bh >> 4, hh = bh & 15;
  __shared__ __align__(16) bf16 Qs[80 * 64];
  __shared__ __align__(16) bf16 Ks[80 * 64];
  __shared__ __align__(16) bf16 Vt[64 * 104];
  __shared__ __align__(16) bf16 Pb[80 * 96];
  __shared__ float Sc[80 * 81];
  int tid = threadIdx.x;
  const bf16* base = qkv + (size_t)(b * NTOK) * 3072 + hh * 64;
  // Q,K with RoPE (pair p: dims 2p,2p+1; p<16 = row-half, p>=16 = col-half)
  for (int idx = tid; idx < NTOK * 32; idx += 256) {
    int n = idx >> 5, p = idx & 31;
    int j = p & 15;
    int pos = (n == 0) ? 0 : ((p < 16) ? ((n - 1) >> 3) : ((n - 1) & 7));
    float inv = __powf(10000.f, -(float)j * (1.f / 16.f));
    float ang = (float)pos * inv;
    float cs = __cosf(ang), sn = __sinf(ang);
    const bf16* qp = base + (size_t)n * 3072 + 2 * p;
    float qe = b2f(qp[0]), qo = b2f(qp[1]);
    Qs[n * 64 + 2 * p] = f2b(qe * cs - qo * sn);
    Qs[n * 64 + 2 * p + 1] = f2b(qo * cs + qe * sn);
    const bf16* kp = qp + 1024;
    float ke = b2f(kp[0]), ko = b2f(kp[1]);
    Ks[n * 64 + 2 * p] = f2b(ke * cs - ko * sn);
    Ks[n * 64 + 2 * p + 1] = f2b(ko * cs + ke * sn);
  }
  // V transposed: Vt[d][m]
  for (int idx = tid; idx < NTOK * 64; idx += 256) {
    int m = idx >> 6, d = idx & 63;
    Vt[d * 104 + m] = base[(size_t)m * 3072 + 2048 + d];
  }
  // zero Vt pad cols (m 65..103) so Pb(0) * Vt(pad) can't be 0*inf
  for (int i = tid; i < 64 * 39; i += 256) {
    int d = i / 39, m = 65 + i % 39;
    Vt[d * 104 + m] = f2b(0.f);
  }
  __syncthreads();
  int w = tid >> 6, lane = tid & 63, quad = lane >> 4, lr = lane & 15;
  // scores = Q @ K^T * scale  (5x5 tiles of 16x16, K-dim 64 = 2 mfma steps)
  for (int t = w; t < 25; t += 4) {
    int mi = t / 5, ni = t % 5;
    f32x4 c = (f32x4){0.f, 0.f, 0.f, 0.f};
    for (int ks = 0; ks < 2; ks++) {
      bf16x8 aq = *reinterpret_cast<const bf16x8*>(&Qs[(mi * 16 + lr) * 64 + ks * 32 + quad * 8]);
      bf16x8 bk = *reinterpret_cast<const bf16x8*>(&Ks[(ni * 16 + lr) * 64 + ks * 32 + quad * 8]);
      c = __builtin_amdgcn_mfma_f32_16x16x32_bf16(aq, bk, c, 0, 0, 0);
    }
    for (int r = 0; r < 4; r++)
      Sc[(mi * 16 + quad * 4 + r) * 81 + ni * 16 + lr] = c[r] * 0.125f;
  }
  __syncthreads();
  // row softmax -> Pb (bf16), zero-padded to 80x96
  if (tid < 80) {
    bf16* pr = &Pb[tid * 96];
    if (tid < NTOK) {
      float* row = &Sc[tid * 81];
      float mx = row[0];
      for (int m = 1; m < NTOK; m++) mx = fmaxf(mx, row[m]);
      float sum = 0.f;
      for (int m = 0; m < NTOK; m++) {
        float e = __expf(row[m] - mx);
        row[m] = e;
        sum += e;
      }
      float is = 1.f / sum;
      for (int m = 0; m < NTOK; m++) pr[m] = f2b(row[m] * is);
      for (int m = NTOK; m < 96; m++) pr[m] = f2b(0.f);
    } else {
      for (int m = 0; m < 96; m++) pr[m] = f2b(0.f);
    }
  }
  __syncthreads();
  // O = P @ V  (5 n-tiles x 4 d-tiles, K-dim 96 = 3 mfma steps)
  for (int t = w; t < 20; t += 4) {
    int mi = t >> 2, di = t & 3;
    f32x4 c = (f32x4){0.f, 0.f, 0.f, 0.f};
    for (int ks = 0; ks < 3; ks++) {
      bf16x8 ap = *reinterpret_cast<const bf16x8*>(&Pb[(mi * 16 + lr) * 96 + ks * 32 + quad * 8]);
      bf16x8 bv = *reinterpret_cast<const bf16x8*>(&Vt[(di * 16 + lr) * 104 + ks * 32 + quad * 8]);
      c = __builtin_amdgcn_mfma_f32_16x16x32_bf16(ap, bv, c, 0, 0, 0);
    }
    for (int r = 0; r < 4; r++) {
      int n = mi * 16 + quad * 4 + r;
      if (n < NTOK)
        O[(size_t)(b * NTOK + n) * DIM + hh * 64 + di * 16 + lr] = f2b(c[r]);
    }
  }
}

extern "C" void kernel_launch(void* const* d_in, const int* in_sizes, int n_in,
                              void* d_out, int out_size, void* d_ws, size_t ws_size,
                              hipStream_t stream) {
  const float* img = (const float*)d_in[0];
  const float* patch_W = (const float*)d_in[1];
  const float* patch_b = (const float*)d_in[2];
  const float* cls_token = (const float*)d_in[3];
  const float* ln1_g = (const float*)d_in[4];
  const float* ln1_b = (const float*)d_in[5];
  const float* Wqkv = (const float*)d_in[6];
  const float* Wproj = (const float*)d_in[7];
  const float* bproj = (const float*)d_in[8];
  const float* ln2_g = (const float*)d_in[9];
  const float* ln2_b = (const float*)d_in[10];
  const float* W1 = (const float*)d_in[11];
  const float* b1 = (const float*)d_in[12];
  const float* W2 = (const float*)d_in[13];
  const float* b2 = (const float*)d_in[14];
  const float* lnf_g = (const float*)d_in[15];
  const float* lnf_b = (const float*)d_in[16];
  float* out = (float*)d_out;

  char* ws = (char*)d_ws;
  size_t off = 0;
  auto alloc = [&](size_t bytes) -> void* {
    void* p = ws + off;
    off += (bytes + 255) & ~(size_t)255;
    return p;
  };
  bf16* wt_patch = (bf16*)alloc((size_t)2 * 1024 * 1024);
  bf16* wt_qkv = (bf16*)alloc((size_t)2 * NLAYER * 1024 * 3072);
  bf16* wt_proj = (bf16*)alloc((size_t)2 * NLAYER * 1024 * 1024);
  bf16* wt_w1 = (bf16*)alloc((size_t)2 * NLAYER * 1024 * 4096);
  bf16* wt_w2 = (bf16*)alloc((size_t)2 * NLAYER * 1024 * 4096);
  float* xbuf = (float*)alloc((size_t)4 * NROWS * DIM);
  bf16* bufA = (bf16*)alloc((size_t)2 * NROWS * DIM);  // h / attn-out / h2
  bf16* bufB = (bf16*)alloc((size_t)2 * NROWS * FDIM); // patches / qkv / mlp-mid
  if (off > ws_size) return; // workspace too small — fail loudly via wrong output

  dim3 tb(32, 8);
  transpose_w<<<dim3(32, 32, 1), tb, 0, stream>>>(patch_W, wt_patch, 1024, 1024);
  transpose_w<<<dim3(96, 32, NLAYER), tb, 0, stream>>>(Wqkv, wt_qkv, 1024, 3072);
  transpose_w<<<dim3(32, 32, NLAYER), tb, 0, stream>>>(Wproj, wt_proj, 1024, 1024);
  transpose_w<<<dim3(128, 32, NLAYER), tb, 0, stream>>>(W1, wt_w1, 1024, 4096);
  transpose_w<<<dim3(32, 128, NLAYER), tb, 0, stream>>>(W2, wt_w2, 4096, 1024);

  im2col_k<<<65536, 256, 0, stream>>>(img, bufB);
  clsfill_k<<<1024, 256, 0, stream>>>(cls_token, xbuf);
  // patch embed: (16384 x 1024) @ (1024 x 1024) + b -> scattered fp32 rows of xbuf
  gemm_bt<3><<<dim3(8, 128), 256, 0, stream>>>(bufB, wt_patch, patch_b, nullptr, xbuf, nullptr,
                                               16384, 1024, 1024);

  for (int l = 0; l < NLAYER; l++) {
    ln_k<<<NROWS, 256, 0, stream>>>(xbuf, ln1_g + l * DIM, ln1_b + l * DIM, bufA);
    gemm_bt<0><<<dim3(24, 130), 256, 0, stream>>>(bufA, wt_qkv + (size_t)l * 3072 * 1024, nullptr,
                                                  nullptr, nullptr, bufB, NROWS, 3072, 1024);
    attn_k<<<BATCH * NHEADS, 256, 0, stream>>>(bufB, bufA);
    gemm_bt<2><<<dim3(8, 130), 256, 0, stream>>>(bufA, wt_proj + (size_t)l * 1024 * 1024,
                                                 bproj + l * DIM, xbuf, xbuf, nullptr, NROWS, 1024, 1024);
    ln_k<<<NROWS, 256, 0, stream>>>(xbuf, ln2_g + l * DIM, ln2_b + l * DIM, bufA);
    gemm_bt<1><<<dim3(32, 130), 256, 0, stream>>>(bufA, wt_w1 + (size_t)l * 4096 * 1024,
                                                  b1 + l * FDIM, nullptr, nullptr, bufB, NROWS, 4096, 1024);
    gemm_bt<2><<<dim3(8, 130), 256, 0, stream>>>(bufB, wt_w2 + (size_t)l * 4096 * 1024,
                                                 b2 + l * DIM, xbuf, xbuf, nullptr, NROWS, 1024, 4096);
  }
  lnf_k<<<BATCH, 256, 0, stream>>>(xbuf, lnf_g, lnf_b, out);
}

// Round 2
// 10396.551 us; speedup vs baseline: 1.0935x; 1.0935x over previous
//
#include <hip/hip_runtime.h>
#include <hip/hip_bf16.h>
#include <math.h>

using bf16 = __hip_bfloat16;
typedef __bf16 bf16x8 __attribute__((ext_vector_type(8)));
typedef float f32x4 __attribute__((ext_vector_type(4)));

#define NTOK 65
#define BATCH 256
#define DIM 1024
#define NROWS (BATCH * NTOK) /* 16640 */
#define FDIM 4096
#define NHEADS 16
#define NLAYER 12

__device__ __forceinline__ float b2f(bf16 v) { return __bfloat162float(v); }
__device__ __forceinline__ bf16 f2b(float v) { return __float2bfloat16(v); }

// async global->LDS, 16B per lane; lds ptr must be wave-uniform (lane i lands at base + i*16B)
__device__ __forceinline__ void load16(const void* g, void* l) {
  __builtin_amdgcn_global_load_lds((const __attribute__((address_space(1))) void*)g,
                                   (__attribute__((address_space(3))) void*)l,
                                   16, 0, 0);
}

// fast erf, A&S 7.1.26, |abs err| <= 1.5e-7 (plenty for 2% rel tolerance)
__device__ __forceinline__ float fast_erf(float x) {
  float ax = fabsf(x);
  float t = 1.f / (1.f + 0.3275911f * ax);
  float y = t * (0.254829592f +
            t * (-0.284496736f +
            t * (1.421413741f +
            t * (-1.453152027f + t * 1.061405429f))));
  float r = 1.f - y * __expf(-ax * ax);
  return copysignf(r, x);
}

// ---------------- weight convert + transpose: W (L,K,N) f32 -> Wt (L,N,K) bf16 ----------------
__global__ __launch_bounds__(256) void transpose_w(const float* __restrict__ W,
                                                   bf16* __restrict__ Wt, int K, int Nn) {
  __shared__ float t[32][33];
  int l = blockIdx.z;
  const float* Wl = W + (size_t)l * K * Nn;
  bf16* Wtl = Wt + (size_t)l * K * Nn;
  int n0 = blockIdx.x * 32, k0 = blockIdx.y * 32;
  int tx = threadIdx.x, ty = threadIdx.y; // 32 x 8
  for (int i = 0; i < 4; i++)
    t[ty + i * 8][tx] = Wl[(size_t)(k0 + ty + i * 8) * Nn + n0 + tx];
  __syncthreads();
  for (int i = 0; i < 4; i++)
    Wtl[(size_t)(n0 + ty + i * 8) * K + k0 + tx] = f2b(t[tx][ty + i * 8]);
}

// ---------------- im2col: img (B,1,256,256) f32 -> patches (B*64, 1024) bf16 ----------------
__global__ __launch_bounds__(256) void im2col_k(const float* __restrict__ img, bf16* __restrict__ out) {
  int idx = blockIdx.x * 256 + threadIdx.x; // 16384*1024 total
  int c = idx & 31, r = (idx >> 5) & 31, p = (idx >> 10) & 63, b = idx >> 16;
  int gr = p >> 3, gc = p & 7;
  out[idx] = f2b(img[((size_t)b << 16) + (size_t)(gr * 32 + r) * 256 + gc * 32 + c]);
}

// ---------------- cls rows of residual stream ----------------
__global__ __launch_bounds__(256) void clsfill_k(const float* __restrict__ cls, float* __restrict__ xbuf) {
  int idx = blockIdx.x * 256 + threadIdx.x; // 256*1024
  int b = idx >> 10, d = idx & 1023;
  xbuf[(size_t)(b * NTOK) * DIM + d] = cls[d];
}

// ---------------- LayerNorm: fp32 row (1024) -> bf16 row ----------------
__global__ __launch_bounds__(256) void ln_k(const float* __restrict__ x, const float* __restrict__ g,
                                            const float* __restrict__ bt, bf16* __restrict__ out) {
  int row = blockIdx.x;
  int t = threadIdx.x;
  float4 v = ((const float4*)(x + (size_t)row * DIM))[t];
  float s = v.x + v.y + v.z + v.w;
  float ss = v.x * v.x + v.y * v.y + v.z * v.z + v.w * v.w;
  for (int off = 32; off > 0; off >>= 1) { s += __shfl_down(s, off, 64); ss += __shfl_down(ss, off, 64); }
  __shared__ float sh[8];
  int w = t >> 6, lane = t & 63;
  if (lane == 0) { sh[w] = s; sh[w + 4] = ss; }
  __syncthreads();
  s = sh[0] + sh[1] + sh[2] + sh[3];
  ss = sh[4] + sh[5] + sh[6] + sh[7];
  float mu = s * (1.f / DIM);
  float rs = rsqrtf(ss * (1.f / DIM) - mu * mu + 1e-5f);
  float4 gv = ((const float4*)g)[t];
  float4 bv = ((const float4*)bt)[t];
  bf16* o = out + (size_t)row * DIM + t * 4;
  o[0] = f2b((v.x - mu) * rs * gv.x + bv.x);
  o[1] = f2b((v.y - mu) * rs * gv.y + bv.y);
  o[2] = f2b((v.z - mu) * rs * gv.z + bv.z);
  o[3] = f2b((v.w - mu) * rs * gv.w + bv.w);
}

// ---------------- final LN on cls rows only -> fp32 d_out ----------------
__global__ __launch_bounds__(256) void lnf_k(const float* __restrict__ x, const float* __restrict__ g,
                                             const float* __restrict__ bt, float* __restrict__ out) {
  int b = blockIdx.x;
  int t = threadIdx.x;
  float4 v = ((const float4*)(x + (size_t)(b * NTOK) * DIM))[t];
  float s = v.x + v.y + v.z + v.w;
  float ss = v.x * v.x + v.y * v.y + v.z * v.z + v.w * v.w;
  for (int off = 32; off > 0; off >>= 1) { s += __shfl_down(s, off, 64); ss += __shfl_down(ss, off, 64); }
  __shared__ float sh[8];
  int w = t >> 6, lane = t & 63;
  if (lane == 0) { sh[w] = s; sh[w + 4] = ss; }
  __syncthreads();
  s = sh[0] + sh[1] + sh[2] + sh[3];
  ss = sh[4] + sh[5] + sh[6] + sh[7];
  float mu = s * (1.f / DIM);
  float rs = rsqrtf(ss * (1.f / DIM) - mu * mu + 1e-5f);
  float4 gv = ((const float4*)g)[t];
  float4 bv = ((const float4*)bt)[t];
  float4 o;
  o.x = (v.x - mu) * rs * gv.x + bv.x;
  o.y = (v.y - mu) * rs * gv.y + bv.y;
  o.z = (v.z - mu) * rs * gv.z + bv.z;
  o.w = (v.w - mu) * rs * gv.w + bv.w;
  ((float4*)(out + (size_t)b * DIM))[t] = o;
}

// ---------------- generic NT GEMM: C[M,Nn] = A[M,K](bf16) @ Bt[Nn,K](bf16)^T ----------------
// BK=64 staged as two side-by-side BK=32 half-panels (keeps 64B LDS row stride ->
// 2-way-free bank pattern, and keeps global_load_lds wave-uniform layout).
// MODE 0: bf16 out, no bias (QKV)
// MODE 1: bias + fast-erf GELU -> bf16 out (MLP1)
// MODE 2: bias + residual -> fp32 out (proj / MLP2)
// MODE 3: bias + row remap (patch embed: row -> row + row/64 + 1) -> fp32 out
template <int MODE>
__global__ __launch_bounds__(256) void gemm_bt(const bf16* __restrict__ A, const bf16* __restrict__ Bt,
                                               const float* __restrict__ bias, const float* __restrict__ res,
                                               float* __restrict__ outf, bf16* __restrict__ outb,
                                               int M, int Nn, int K) {
  __shared__ __align__(16) bf16 As[2 * 128 * 32]; // [half][row][32k]
  __shared__ __align__(16) bf16 Bs[2 * 128 * 32];
  int tid = threadIdx.x;
  int w = tid >> 6, lane = tid & 63;
  int quad = lane >> 4, lr = lane & 15;

  // supertile swizzle: 32-row bands, column-fastest within band (A-panels stay L2-hot per XCD)
  int gx = gridDim.x, gy = gridDim.y;
  int lin = blockIdx.y * gx + blockIdx.x;
  const int T = 32;
  int group = T * gx;
  int g = lin / group;
  int r = lin - g * group;
  int rows = min(T, gy - g * T);
  int tyy = g * T + r % rows;
  int txx = r / rows;
  int m0 = tyy * 128, n0 = txx * 128;

  int srow = w * 32 + (lane >> 2);
  int skoff = (lane & 3) * 8;
  const bf16* Ag = A + (size_t)(m0 + srow) * K + skoff;
  const bf16* Bg = Bt + (size_t)(n0 + srow) * K + skoff;
  bf16* AsW = &As[w * 1024];
  bf16* BsW = &Bs[w * 1024];
  int wm = (w >> 1) * 64, wn = (w & 1) * 64;
  f32x4 acc[4][4];
  for (int i = 0; i < 4; i++)
    for (int j = 0; j < 4; j++) acc[i][j] = (f32x4){0.f, 0.f, 0.f, 0.f};

  for (int kb = 0; kb < K; kb += 64) {
    // half 0 (k .. k+31)
    load16(Ag + kb, AsW);
    load16(Ag + kb + (size_t)16 * K, AsW + 512);
    load16(Bg + kb, BsW);
    load16(Bg + kb + (size_t)16 * K, BsW + 512);
    // half 1 (k+32 .. k+63)
    load16(Ag + kb + 32, AsW + 4096);
    load16(Ag + kb + 32 + (size_t)16 * K, AsW + 4096 + 512);
    load16(Bg + kb + 32, BsW + 4096);
    load16(Bg + kb + 32 + (size_t)16 * K, BsW + 4096 + 512);
    __syncthreads();
#pragma unroll
    for (int h = 0; h < 2; h++) {
      bf16x8 af[4], bfr[4];
      const bf16* Ah = &As[h * 4096];
      const bf16* Bh = &Bs[h * 4096];
#pragma unroll
      for (int i = 0; i < 4; i++)
        af[i] = *reinterpret_cast<const bf16x8*>(&Ah[(wm + i * 16 + lr) * 32 + quad * 8]);
#pragma unroll
      for (int i = 0; i < 4; i++)
        bfr[i] = *reinterpret_cast<const bf16x8*>(&Bh[(wn + i * 16 + lr) * 32 + quad * 8]);
#pragma unroll
      for (int mi = 0; mi < 4; mi++)
#pragma unroll
        for (int ni = 0; ni < 4; ni++)
          acc[mi][ni] = __builtin_amdgcn_mfma_f32_16x16x32_bf16(af[mi], bfr[ni], acc[mi][ni], 0, 0, 0);
    }
    __syncthreads();
  }

  for (int mi = 0; mi < 4; mi++)
    for (int ni = 0; ni < 4; ni++)
      for (int rr = 0; rr < 4; rr++) {
        int grow = m0 + wm + mi * 16 + quad * 4 + rr;
        int gcol = n0 + wn + ni * 16 + lr;
        float v = acc[mi][ni][rr];
        if (MODE == 0) {
          outb[(size_t)grow * Nn + gcol] = f2b(v);
        } else if (MODE == 1) {
          v += bias[gcol];
          v = 0.5f * v * (1.f + fast_erf(v * 0.70710678118f));
          outb[(size_t)grow * Nn + gcol] = f2b(v);
        } else if (MODE == 2) {
          size_t o = (size_t)grow * Nn + gcol;
          outf[o] = res[o] + v + bias[gcol];
        } else {
          int prow = grow + (grow >> 6) + 1; // b*64+p -> b*65+1+p
          outf[(size_t)prow * DIM + gcol] = v + bias[gcol];
        }
      }
}

// ---------------- attention: one block per (b,h); RoPE on load; MFMA QK^T and PV ----------------
__global__ __launch_bounds__(256) void attn_k(const bf16* __restrict__ qkv, bf16* __restrict__ O) {
  int bh = blockIdx.x;
  int b = bh >> 4, hh = bh & 15;
  __shared__ __align__(16) bf16 Qs[80 * 64];
  __shared__ __align__(16) bf16 Ks[80 * 64];
  __shared__ __align__(16) bf16 Vt[64 * 104];
  __shared__ __align__(16) bf16 Pb[80 * 96];
  __shared__ float Sc[80 * 81];
  int tid = threadIdx.x;
  const bf16* base = qkv + (size_t)(b * NTOK) * 3072 + hh * 64;
  // Q,K with RoPE (pair p: dims 2p,2p+1; p<16 = row-half, p>=16 = col-half)
  for (int idx = tid; idx < NTOK * 32; idx += 256) {
    int n = idx >> 5, p = idx & 31;
    int j = p & 15;
    int pos = (n == 0) ? 0 : ((p < 16) ? ((n - 1) >> 3) : ((n - 1) & 7));
    float inv = __powf(10000.f, -(float)j * (1.f / 16.f));
    float ang = (float)pos * inv;
    float cs = __cosf(ang), sn = __sinf(ang);
    const bf16* qp = base + (size_t)n * 3072 + 2 * p;
    float qe = b2f(qp[0]), qo = b2f(qp[1]);
    Qs[n * 64 + 2 * p] = f2b(qe * cs - qo * sn);
    Qs[n * 64 + 2 * p + 1] = f2b(qo * cs + qe * sn);
    const bf16* kp = qp + 1024;
    float ke = b2f(kp[0]), ko = b2f(kp[1]);
    Ks[n * 64 + 2 * p] = f2b(ke * cs - ko * sn);
    Ks[n * 64 + 2 * p + 1] = f2b(ko * cs + ke * sn);
  }
  // V transposed: Vt[d][m]
  for (int idx = tid; idx < NTOK * 64; idx += 256) {
    int m = idx >> 6, d = idx & 63;
    Vt[d * 104 + m] = base[(size_t)m * 3072 + 2048 + d];
  }
  // zero Vt pad cols (m 65..103) so Pb(0) * Vt(pad) can't be 0*inf
  for (int i = tid; i < 64 * 39; i += 256) {
    int d = i / 39, m = 65 + i % 39;
    Vt[d * 104 + m] = f2b(0.f);
  }
  __syncthreads();
  int w = tid >> 6, lane = tid & 63, quad = lane >> 4, lr = lane & 15;
  // scores = Q @ K^T * scale  (5x5 tiles of 16x16, K-dim 64 = 2 mfma steps)
  for (int t = w; t < 25; t += 4) {
    int mi = t / 5, ni = t % 5;
    f32x4 c = (f32x4){0.f, 0.f, 0.f, 0.f};
    for (int ks = 0; ks < 2; ks++) {
      bf16x8 aq = *reinterpret_cast<const bf16x8*>(&Qs[(mi * 16 + lr) * 64 + ks * 32 + quad * 8]);
      bf16x8 bk = *reinterpret_cast<const bf16x8*>(&Ks[(ni * 16 + lr) * 64 + ks * 32 + quad * 8]);
      c = __builtin_amdgcn_mfma_f32_16x16x32_bf16(aq, bk, c, 0, 0, 0);
    }
    for (int r = 0; r < 4; r++)
      Sc[(mi * 16 + quad * 4 + r) * 81 + ni * 16 + lr] = c[r] * 0.125f;
  }
  __syncthreads();
  // row softmax -> Pb (bf16), zero-padded to 80x96
  if (tid < 80) {
    bf16* pr = &Pb[tid * 96];
    if (tid < NTOK) {
      float* row = &Sc[tid * 81];
      float mx = row[0];
      for (int m = 1; m < NTOK; m++) mx = fmaxf(mx, row[m]);
      float sum = 0.f;
      for (int m = 0; m < NTOK; m++) {
        float e = __expf(row[m] - mx);
        row[m] = e;
        sum += e;
      }
      float is = 1.f / sum;
      for (int m = 0; m < NTOK; m++) pr[m] = f2b(row[m] * is);
      for (int m = NTOK; m < 96; m++) pr[m] = f2b(0.f);
    } else {
      for (int m = 0; m < 96; m++) pr[m] = f2b(0.f);
    }
  }
  __syncthreads();
  // O = P @ V  (5 n-tiles x 4 d-tiles, K-dim 96 = 3 mfma steps)
  for (int t = w; t < 20; t += 4) {
    int mi = t >> 2, di = t & 3;
    f32x4 c = (f32x4){0.f, 0.f, 0.f, 0.f};
    for (int ks = 0; ks < 3; ks++) {
      bf16x8 ap = *reinterpret_cast<const bf16x8*>(&Pb[(mi * 16 + lr) * 96 + ks * 32 + quad * 8]);
      bf16x8 bv = *reinterpret_cast<const bf16x8*>(&Vt[(di * 16 + lr) * 104 + ks * 32 + quad * 8]);
      c = __builtin_amdgcn_mfma_f32_16x16x32_bf16(ap, bv, c, 0, 0, 0);
    }
    for (int r = 0; r < 4; r++) {
      int n = mi * 16 + quad * 4 + r;
      if (n < NTOK)
        O[(size_t)(b * NTOK + n) * DIM + hh * 64 + di * 16 + lr] = f2b(c[r]);
    }
  }
}

extern "C" void kernel_launch(void* const* d_in, const int* in_sizes, int n_in,
                              void* d_out, int out_size, void* d_ws, size_t ws_size,
                              hipStream_t stream) {
  const float* img = (const float*)d_in[0];
  const float* patch_W = (const float*)d_in[1];
  const float* patch_b = (const float*)d_in[2];
  const float* cls_token = (const float*)d_in[3];
  const float* ln1_g = (const float*)d_in[4];
  const float* ln1_b = (const float*)d_in[5];
  const float* Wqkv = (const float*)d_in[6];
  const float* Wproj = (const float*)d_in[7];
  const float* bproj = (const float*)d_in[8];
  const float* ln2_g = (const float*)d_in[9];
  const float* ln2_b = (const float*)d_in[10];
  const float* W1 = (const float*)d_in[11];
  const float* b1 = (const float*)d_in[12];
  const float* W2 = (const float*)d_in[13];
  const float* b2 = (const float*)d_in[14];
  const float* lnf_g = (const float*)d_in[15];
  const float* lnf_b = (const float*)d_in[16];
  float* out = (float*)d_out;

  char* ws = (char*)d_ws;
  size_t off = 0;
  auto alloc = [&](size_t bytes) -> void* {
    void* p = ws + off;
    off += (bytes + 255) & ~(size_t)255;
    return p;
  };
  bf16* wt_patch = (bf16*)alloc((size_t)2 * 1024 * 1024);
  bf16* wt_qkv = (bf16*)alloc((size_t)2 * NLAYER * 1024 * 3072);
  bf16* wt_proj = (bf16*)alloc((size_t)2 * NLAYER * 1024 * 1024);
  bf16* wt_w1 = (bf16*)alloc((size_t)2 * NLAYER * 1024 * 4096);
  bf16* wt_w2 = (bf16*)alloc((size_t)2 * NLAYER * 1024 * 4096);
  float* xbuf = (float*)alloc((size_t)4 * NROWS * DIM);
  bf16* bufA = (bf16*)alloc((size_t)2 * NROWS * DIM);  // h / attn-out / h2
  bf16* bufB = (bf16*)alloc((size_t)2 * NROWS * FDIM); // patches / qkv / mlp-mid
  if (off > ws_size) return; // workspace too small — fail loudly via wrong output

  dim3 tb(32, 8);
  transpose_w<<<dim3(32, 32, 1), tb, 0, stream>>>(patch_W, wt_patch, 1024, 1024);
  transpose_w<<<dim3(96, 32, NLAYER), tb, 0, stream>>>(Wqkv, wt_qkv, 1024, 3072);
  transpose_w<<<dim3(32, 32, NLAYER), tb, 0, stream>>>(Wproj, wt_proj, 1024, 1024);
  transpose_w<<<dim3(128, 32, NLAYER), tb, 0, stream>>>(W1, wt_w1, 1024, 4096);
  transpose_w<<<dim3(32, 128, NLAYER), tb, 0, stream>>>(W2, wt_w2, 4096, 1024);

  im2col_k<<<65536, 256, 0, stream>>>(img, bufB);
  clsfill_k<<<1024, 256, 0, stream>>>(cls_token, xbuf);
  // patch embed: (16384 x 1024) @ (1024 x 1024) + b -> scattered fp32 rows of xbuf
  gemm_bt<3><<<dim3(8, 128), 256, 0, stream>>>(bufB, wt_patch, patch_b, nullptr, xbuf, nullptr,
                                               16384, 1024, 1024);

  for (int l = 0; l < NLAYER; l++) {
    ln_k<<<NROWS, 256, 0, stream>>>(xbuf, ln1_g + l * DIM, ln1_b + l * DIM, bufA);
    gemm_bt<0><<<dim3(24, 130), 256, 0, stream>>>(bufA, wt_qkv + (size_t)l * 3072 * 1024, nullptr,
                                                  nullptr, nullptr, bufB, NROWS, 3072, 1024);
    attn_k<<<BATCH * NHEADS, 256, 0, stream>>>(bufB, bufA);
    gemm_bt<2><<<dim3(8, 130), 256, 0, stream>>>(bufA, wt_proj + (size_t)l * 1024 * 1024,
                                                 bproj + l * DIM, xbuf, xbuf, nullptr, NROWS, 1024, 1024);
    ln_k<<<NROWS, 256, 0, stream>>>(xbuf, ln2_g + l * DIM, ln2_b + l * DIM, bufA);
    gemm_bt<1><<<dim3(32, 130), 256, 0, stream>>>(bufA, wt_w1 + (size_t)l * 4096 * 1024,
                                                  b1 + l * FDIM, nullptr, nullptr, bufB, NROWS, 4096, 1024);
    gemm_bt<2><<<dim3(8, 130), 256, 0, stream>>>(bufB, wt_w2 + (size_t)l * 4096 * 1024,
                                                 b2 + l * DIM, xbuf, xbuf, nullptr, NROWS, 1024, 4096);
  }
  lnf_k<<<BATCH, 256, 0, stream>>>(xbuf, lnf_g, lnf_b, out);
}